// Round 7
// baseline (461.246 us; speedup 1.0000x reference)
//
#include <hip/hip_runtime.h>

#define BATCH 16384
#define NUM   512
#define CONS  512
#define ROWS  64                    // rows per block (one wave)
#define NPAD  (CONS + 8)
#define EPW   48                    // words per (c,g) record

typedef _Float16 h4 __attribute__((ext_vector_type(4)));   // 4 rows (8 B)
typedef _Float16 h8 __attribute__((ext_vector_type(8)));   // 8 rows (16 B)

static __device__ __forceinline__ h4 hmax4(h4 a, h4 b){ return __builtin_elementwise_max(a,b); }
static __device__ __forceinline__ h4 hmin4(h4 a, h4 b){ return __builtin_elementwise_min(a,b); }
static __device__ __forceinline__ uint2 h2u2(h4 h){ return __builtin_bit_cast(uint2,h); }
static __device__ __forceinline__ h4 u22h(uint2 u){ return __builtin_bit_cast(h4,u); }
static __device__ __forceinline__ h4 shflx(h4 x, int m) {
  uint2 u = h2u2(x);
  u.x = (unsigned)__shfl_xor((int)u.x, m, 64);
  u.y = (unsigned)__shfl_xor((int)u.y, m, 64);
  return u22h(u);
}

// record per (c,g): [0..15] N offs, [16..31] P offs, [32..37] N extra, [38..43] P extra,
// [44] ho, [45] fl, [46..47] pad.   offsets are atom*128.
// fl: 0 sign | 1 N1 | 2 P1 | 3 N2 | 4 P2 | 5 PR1 | 6 PR2 | 8-11 exN | 12-15 exP |
//     16 EN | 17 EP | 18 SKIP
__global__ __launch_bounds__(64) void prep_kernel(
    const float* __restrict__ pos, const float* __restrict__ neg,
    const int* __restrict__ head_atom, const int* __restrict__ head_sign,
    unsigned* __restrict__ ents) {
  int c = blockIdx.x, lane = threadIdx.x;
  unsigned* rec = ents + (size_t)c * (4 * EPW);
  if (c >= CONS) {
    for (int t = lane; t < 4 * EPW; t += 64) {
      int k = t % EPW;
      rec[t] = (k == 45) ? ((1u<<18)|(1u<<16)|(1u<<17)) : 0u;   // SKIP|EN|EP
    }
    return;
  }
  __shared__ unsigned short LN[96], LP[96];
  int hp1 = (c >= 1) ? head_atom[c-1] : -1;
  int hp2 = (c >= 2) ? head_atom[c-2] : -1;
  int nN = 0, nP = 0;
  bool fN1=false, fP1=false, fN2=false, fP2=false;
  for (int k = 0; k < NUM/64; ++k) {
    int a = k*64 + lane;
    bool ln = neg[(size_t)c*NUM + a] != 0.f;
    bool lp = pos[(size_t)c*NUM + a] != 0.f;
    bool n1 = ln && (a == hp1), n2 = ln && (a == hp2);
    bool p1 = lp && (a == hp1), p2 = lp && (a == hp2);
    fN1 |= (__ballot(n1) != 0ull); fN2 |= (__ballot(n2) != 0ull);
    fP1 |= (__ballot(p1) != 0ull); fP2 |= (__ballot(p2) != 0ull);
    bool kn = ln && !n1 && !n2;
    bool kp = lp && !p1 && !p2;
    unsigned long long mn = __ballot(kn), mp = __ballot(kp);
    unsigned long long lt = (1ull << lane) - 1ull;
    int rn = nN + (int)__popcll(mn & lt);
    int rp = nP + (int)__popcll(mp & lt);
    if (kn && rn < 96) LN[rn] = (unsigned short)a;
    if (kp && rp < 96) LP[rp] = (unsigned short)a;
    nN += (int)__popcll(mn);
    nP += (int)__popcll(mp);
  }
  __syncthreads();
  if (nN > 88) nN = 88;
  if (nP > 88) nP = 88;
  unsigned exN = nN > 64 ? (unsigned)((nN - 64 + 3) >> 2) : 0u;
  unsigned exP = nP > 64 ? (unsigned)((nP - 64 + 3) >> 2) : 0u;
  unsigned fl = 0;
  if (head_sign[c]) fl |= 1u;
  if (fN1) fl |= 2u;   if (fP1) fl |= 4u;
  if (fN2) fl |= 8u;   if (fP2) fl |= 16u;
  int hc = head_atom[c];
  if (hc == hp1) fl |= 32u; else if (hc == hp2) fl |= 64u;
  fl |= (exN << 8) | (exP << 12);
  if (nN == 0) fl |= 1u << 16;
  if (nP == 0) fl |= 1u << 17;
  unsigned ho = (unsigned)hc * 128u;
  for (int t = lane; t < 4 * EPW; t += 64) {
    int g = t / EPW, k = t % EPW;
    unsigned v;
    if (k < 16)      { int r = k*4 + g;            v = (r < nN) ? LN[r]*128u : (nN ? LN[0]*128u : 0u); }
    else if (k < 32) { int r = (k-16)*4 + g;       v = (r < nP) ? LP[r]*128u : (nP ? LP[0]*128u : 0u); }
    else if (k < 38) { int r = 64 + (k-32)*4 + g;  v = (r < nN) ? LN[r]*128u : (nN ? LN[0]*128u : 0u); }
    else if (k < 44) { int r = 64 + (k-38)*4 + g;  v = (r < nP) ? LP[r]*128u : (nP ? LP[0]*128u : 0u); }
    else if (k == 44) v = ho;
    else if (k == 45) v = fl;
    else v = 0;
    rec[t] = v;
  }
}

struct ENT { uint4 q[8]; unsigned ho, fl; };
struct RD  { h4 v[32]; h4 pv; unsigned ho, fl; int c; };
struct ST  { h4 braw, prevraw; unsigned ho, fl; int c; };

static __device__ __forceinline__ ENT ldent(const unsigned* ents, int c, int g) {
  const unsigned* rec = ents + ((size_t)c * 4 + g) * EPW;
  ENT e;
  #pragma unroll
  for (int j = 0; j < 8; ++j) e.q[j] = ((const uint4*)rec)[j];
  uint2 m = *(const uint2*)(rec + 44);
  e.ho = m.x; e.fl = m.y;
  return e;
}
static __device__ __forceinline__ void issue_reads(const ENT& E, int c, const char* Pb,
                                                   unsigned pr8, RD& R) {
  #pragma unroll
  for (int j = 0; j < 8; ++j) {
    uint4 q = E.q[j];
    R.v[4*j+0] = *(const h4*)(Pb + (q.x + pr8));
    R.v[4*j+1] = *(const h4*)(Pb + (q.y + pr8));
    R.v[4*j+2] = *(const h4*)(Pb + (q.z + pr8));
    R.v[4*j+3] = *(const h4*)(Pb + (q.w + pr8));
  }
  R.pv = *(const h4*)(Pb + (E.ho + pr8));
  R.ho = E.ho; R.fl = E.fl; R.c = c;
}
static __device__ __forceinline__ void combine(const RD& R, const unsigned* ents,
                                               const char* Pb, unsigned pr8, int g, ST& S) {
  h4 aN = hmax4(hmax4(hmax4(hmax4(R.v[0],R.v[1]),  hmax4(R.v[2],R.v[3])),
                      hmax4(hmax4(R.v[4],R.v[5]),  hmax4(R.v[6],R.v[7]))),
                hmax4(hmax4(hmax4(R.v[8],R.v[9]),  hmax4(R.v[10],R.v[11])),
                      hmax4(hmax4(R.v[12],R.v[13]),hmax4(R.v[14],R.v[15]))));
  h4 aP = hmin4(hmin4(hmin4(hmin4(R.v[16],R.v[17]),hmin4(R.v[18],R.v[19])),
                      hmin4(hmin4(R.v[20],R.v[21]),hmin4(R.v[22],R.v[23]))),
                hmin4(hmin4(hmin4(R.v[24],R.v[25]),hmin4(R.v[26],R.v[27])),
                      hmin4(hmin4(R.v[28],R.v[29]),hmin4(R.v[30],R.v[31]))));
  unsigned fl = R.fl;
  if (fl & 0xFF00u) {            // rare overflow tail (>64 literals in a sign)
    const unsigned* rec = ents + ((size_t)R.c * 4 + g) * EPW;
    unsigned xn = (fl >> 8) & 0xFu, xp = (fl >> 12) & 0xFu;
    for (unsigned j = 0; j < xn; ++j)
      aN = hmax4(aN, *(const h4*)(Pb + (rec[32+j] + pr8)));
    for (unsigned j = 0; j < xp; ++j)
      aP = hmin4(aP, *(const h4*)(Pb + (rec[38+j] + pr8)));
  }
  const h4 one4 = {(_Float16)1.f,(_Float16)1.f,(_Float16)1.f,(_Float16)1.f};
  unsigned mEN = ((fl >> 16) & 1u) + 0xFFFFFFFFu;   // bit set -> 0, clear -> ~0
  unsigned mEP = ((fl >> 17) & 1u) + 0xFFFFFFFFu;
  uint2 an = h2u2(aN); an.x &= mEN; an.y &= mEN; aN = u22h(an);
  uint2 ap = h2u2(aP), o2 = h2u2(one4);
  ap.x = (ap.x & mEP) | (o2.x & ~mEP);
  ap.y = (ap.y & mEP) | (o2.y & ~mEP);
  aP = u22h(ap);
  h4 bp = hmax4(aN, one4 - aP);        // >= 0 (aN floor 0 when EN)
  bp = hmax4(bp, shflx(bp, 16));
  bp = hmax4(bp, shflx(bp, 32));
  S.braw = bp; S.prevraw = R.pv; S.ho = R.ho; S.fl = fl; S.c = R.c;
}
static __device__ __forceinline__ h4 finalize(const ST& S, h4 up1, h4 up2,
                                              char* Pb, unsigned pr8, int lane) {
  const h4 one4 = {(_Float16)1.f,(_Float16)1.f,(_Float16)1.f,(_Float16)1.f};
  unsigned fl = S.fl;
  uint2 u1 = h2u2(up1), u2v = h2u2(up2);
  uint2 i1 = h2u2(one4 - up1), i2 = h2u2(one4 - up2);
  unsigned mN1 = 0u-((fl>>1)&1u), mP1 = 0u-((fl>>2)&1u);
  unsigned mN2 = 0u-((fl>>3)&1u), mP2 = 0u-((fl>>4)&1u);
  h4 b = S.braw;
  b = hmax4(b, u22h(uint2{u1.x & mN1,  u1.y & mN1}));
  b = hmax4(b, u22h(uint2{i1.x & mP1,  i1.y & mP1}));
  b = hmax4(b, u22h(uint2{u2v.x & mN2, u2v.y & mN2}));
  b = hmax4(b, u22h(uint2{i2.x & mP2,  i2.y & mP2}));
  unsigned mR1 = 0u-((fl>>5)&1u), mR2 = 0u-((fl>>6)&1u), mRn = ~(mR1|mR2);
  uint2 pv = h2u2(S.prevraw);
  h4 prev = u22h(uint2{(u1.x&mR1)|(u2v.x&mR2)|(pv.x&mRn),
                       (u1.y&mR1)|(u2v.y&mR2)|(pv.y&mRn)});
  unsigned ms = 0u-(fl&1u);
  uint2 hi = h2u2(hmax4(prev, one4 - b));
  uint2 lo = h2u2(hmin4(prev, b));
  h4 upd = u22h(uint2{(hi.x&ms)|(lo.x&~ms), (hi.y&ms)|(lo.y&~ms)});
  if ((lane < 16) && !(fl & (1u<<18)))
    *(h4*)(Pb + S.ho + pr8) = upd;
  return upd;
}

__global__ __launch_bounds__(64, 1) void solve_kernel(
    const float* __restrict__ preds,
    const unsigned* __restrict__ ents,
    float* __restrict__ out) {
  __shared__ char Pb[NUM * 128];          // [atom][64 rows fp16] = 64 KB exactly
  const int lane = threadIdx.x;
  const int g = lane >> 4;                // literal group (4)
  const unsigned pr8 = (unsigned)(lane & 15) * 8u;   // row-quad byte offset
  const size_t row0 = (size_t)blockIdx.x * ROWS;

  // stage in: per iter, lane holds 8 rows of one atom -> ds_write_b128
  #pragma unroll 2
  for (int it = 0; it < 64; ++it) {
    int ac = it & 7, rc = it >> 3;
    int a = ac * 64 + lane;
    int r = rc * 8;
    const float* s = preds + (row0 + r) * NUM + a;
    h8 h;
    #pragma unroll
    for (int j = 0; j < 8; ++j) h[j] = (_Float16)s[(size_t)j * NUM];
    *(h8*)(Pb + a * 128 + r * 2) = h;
  }
  __syncthreads();

  ENT E0 = ldent(ents, 0, g), E1 = ldent(ents, 1, g);
  ENT E2 = ldent(ents, 2, g), E3 = ldent(ents, 3, g);
  RD RA, RB; ST SA, SB;
  issue_reads(E0, 0, Pb, pr8, RA);
  issue_reads(E1, 1, Pb, pr8, RB);
  combine(RA, ents, Pb, pr8, g, SA);
  h4 up1 = (h4)0.0f, up2 = (h4)0.0f;

  #pragma unroll 1
  for (int i = 0; i < CONS; i += 2) {
    issue_reads(E2, i+2, Pb, pr8, RA);                                  // reads(i+2)
    { h4 u = finalize(SA, up1, up2, Pb, pr8, lane); up2 = up1; up1 = u; }  // c=i
    combine(RB, ents, Pb, pr8, g, SB);                                  // c=i+1
    E2 = ldent(ents, i+4, g);
    issue_reads(E3, i+3, Pb, pr8, RB);                                  // reads(i+3)
    { h4 u = finalize(SB, up1, up2, Pb, pr8, lane); up2 = up1; up1 = u; }  // c=i+1
    combine(RA, ents, Pb, pr8, g, SA);                                  // c=i+2
    E3 = ldent(ents, i+5, g);
  }

  __syncthreads();
  #pragma unroll 2
  for (int it = 0; it < 64; ++it) {
    int ac = it & 7, rc = it >> 3;
    int a = ac * 64 + lane;
    int r = rc * 8;
    h8 h = *(const h8*)(Pb + a * 128 + r * 2);
    float* d = out + (row0 + r) * NUM + a;
    #pragma unroll
    for (int j = 0; j < 8; ++j) d[(size_t)j * NUM] = (float)h[j];
  }
}

extern "C" void kernel_launch(void* const* d_in, const int* in_sizes, int n_in,
                              void* d_out, int out_size, void* d_ws, size_t ws_size,
                              hipStream_t stream) {
  (void)in_sizes; (void)n_in; (void)out_size; (void)ws_size;
  const float* preds     = (const float*)d_in[0];
  const float* pos       = (const float*)d_in[1];
  const float* neg       = (const float*)d_in[2];
  const int*   head_atom = (const int*)d_in[3];
  const int*   head_sign = (const int*)d_in[4];

  unsigned* ents = (unsigned*)d_ws;    // NPAD*4*EPW*4 = 399,360 B

  prep_kernel<<<NPAD, 64, 0, stream>>>(pos, neg, head_atom, head_sign, ents);
  solve_kernel<<<BATCH / ROWS, 64, 0, stream>>>(preds, ents, (float*)d_out);
}

// Round 8
// 278.305 us; speedup vs baseline: 1.6573x; 1.6573x over previous
//
#include <hip/hip_runtime.h>

#define BATCH 16384
#define NUM   512
#define CONS  512
#define ROWS  8                     // rows per wave/block
#define ZOFF  (NUM*16)              // zeros scratch (neg dummy), 8192
#define OOFF  (NUM*16 + 16)         // ones scratch (pos dummy), 8208
#define LDSB  (NUM*16 + 32)         // 8224 B
#define NPAD  (CONS + 4)
#define RSTR  84                    // record words per constraint

typedef _Float16 h2 __attribute__((ext_vector_type(2)));
static __device__ __forceinline__ h2 u2h(unsigned u){ return __builtin_bit_cast(h2,u); }
static __device__ __forceinline__ unsigned h2u(h2 h){ return __builtin_bit_cast(unsigned,h); }
static __device__ __forceinline__ h2 hmax2(h2 a,h2 b){ return __builtin_elementwise_max(a,b); }
static __device__ __forceinline__ h2 hmin2(h2 a,h2 b){ return __builtin_elementwise_min(a,b); }
template<int C>
static __device__ __forceinline__ h2 rormax(h2 x) {
  unsigned v = (unsigned)__builtin_amdgcn_mov_dpp((int)h2u(x), C, 0xF, 0xF, true);
  return hmax2(x, u2h(v));
}

// record (RSTR words per c):
// [0..15]=N steps(0,1) packed u16 pairs by g; [16..31]=N steps(2,3);
// [32..47]=P steps(0,1); [48..63]=P steps(2,3); [64]= ho | fl<<16;
// [65..72]=N extras; [73..80]=P extras; [81..83]=pad.
// fl: 0 sign |1 N1 |2 P1 |3 N2 |4 P2 |5 PR1 |6 PR2 |7-10 exN |11-14 exP |15 SKIP
__global__ __launch_bounds__(64) void prep_kernel(
    const float* __restrict__ pos, const float* __restrict__ neg,
    const int* __restrict__ head_atom, const int* __restrict__ head_sign,
    unsigned* __restrict__ ents) {
  int c = blockIdx.x, lane = threadIdx.x;
  unsigned* rec = ents + (size_t)c * RSTR;
  if (c >= CONS) {
    for (int t = lane; t < RSTR; t += 64) {
      unsigned v = 0;
      if (t < 32) v = 0x20002000u;            // ZOFF|ZOFF<<16
      else if (t < 64) v = 0x20102010u;       // OOFF|OOFF<<16
      else if (t == 64) v = 0x8000u << 16;    // SKIP
      else if (t < 73) v = ZOFF;
      else if (t < 81) v = OOFF;
      rec[t] = v;
    }
    return;
  }
  __shared__ unsigned short LN[96], LP[96];
  __shared__ unsigned short slotN[64], slotP[64];
  __shared__ unsigned char usedN[64], usedP[64];
  __shared__ unsigned short spill[16][8];
  __shared__ int spn[16];
  __shared__ unsigned short exN[8], exP[8];
  __shared__ int exn, exp_;
  slotN[lane] = ZOFF; slotP[lane] = OOFF;
  usedN[lane] = 0;    usedP[lane] = 0;
  if (lane < 8) { exN[lane] = ZOFF; exP[lane] = OOFF; }
  if (lane < 16) spn[lane] = 0;
  __syncthreads();

  int hp1 = (c >= 1) ? head_atom[c-1] : -1;
  int hp2 = (c >= 2) ? head_atom[c-2] : -1;
  int nN = 0, nP = 0;
  bool fN1=false, fP1=false, fN2=false, fP2=false;
  for (int k = 0; k < NUM/64; ++k) {
    int a = k*64 + lane;
    bool ln = neg[(size_t)c*NUM + a] != 0.f;
    bool lp = pos[(size_t)c*NUM + a] != 0.f;
    bool n1 = ln && (a == hp1), n2 = ln && (a == hp2);
    bool p1 = lp && (a == hp1), p2 = lp && (a == hp2);
    fN1 |= (__ballot(n1) != 0ull); fN2 |= (__ballot(n2) != 0ull);
    fP1 |= (__ballot(p1) != 0ull); fP2 |= (__ballot(p2) != 0ull);
    bool kn = ln && !n1 && !n2;
    bool kp = lp && !p1 && !p2;
    unsigned long long mn = __ballot(kn), mp = __ballot(kp);
    unsigned long long lt = (1ull << lane) - 1ull;
    int rn = nN + (int)__popcll(mn & lt);
    int rp = nP + (int)__popcll(mp & lt);
    if (kn && rn < 96) LN[rn] = (unsigned short)a;
    if (kp && rp < 96) LP[rp] = (unsigned short)a;
    nN += (int)__popcll(mn);
    nP += (int)__popcll(mp);
  }
  __syncthreads();
  // residue dealing: lane t<8 -> residue t of N; t in 8..15 -> residue t-8 of P
  if (lane < 16) {
    int r = lane & 7;
    bool isP = lane >= 8;
    const unsigned short* L = isP ? LP : LN;
    int n = isP ? nP : nN; if (n > 96) n = 96;
    unsigned short* slot = isP ? slotP : slotN;
    unsigned char* used = isP ? usedP : usedN;
    int rr = 0;
    for (int t = 0; t < n; ++t) {
      int a = L[t];
      if ((a & 7) == r) {
        if (rr < 8) { int s = rr*8 + r; slot[s] = (unsigned short)(a*16); used[s] = 1; }
        else if (rr < 16) spill[lane][rr-8] = (unsigned short)(a*16);
        ++rr;
      }
    }
    spn[lane] = rr > 8 ? (rr > 16 ? 8 : rr - 8) : 0;
  }
  __syncthreads();
  if (lane < 2) {                       // spill placement (serial, tiny)
    bool isP = lane == 1;
    unsigned short* slot = isP ? slotP : slotN;
    unsigned char* used = isP ? usedP : usedN;
    unsigned short* exb = isP ? exP : exN;
    int base = isP ? 8 : 0;
    int e = 0, scan = 0;
    for (int r = 0; r < 8; ++r) {
      int ns = spn[base + r];
      for (int k = 0; k < ns; ++k) {
        unsigned short v = spill[base + r][k];
        while (scan < 64 && used[scan]) ++scan;
        if (scan < 64) { slot[scan] = v; used[scan] = 1; }
        else if (e < 8) exb[e++] = v;
      }
    }
    if (isP) exp_ = e; else exn = e;
  }
  __syncthreads();

  int hc = head_atom[c];
  unsigned fl = 0;
  if (head_sign[c]) fl |= 1u;
  if (fN1) fl |= 2u;  if (fP1) fl |= 4u;
  if (fN2) fl |= 8u;  if (fP2) fl |= 16u;
  if (hc == hp1) fl |= 32u; else if (hc == hp2) fl |= 64u;
  fl |= ((unsigned)exn << 7) | ((unsigned)exp_ << 11);
  unsigned ho = (unsigned)hc * 16u;
  for (int t = lane; t < RSTR; t += 64) {
    unsigned v;
    if (t < 32) {
      int jp = t >> 4, g = t & 15;
      v = (unsigned)slotN[32*jp + g] | ((unsigned)slotN[32*jp + 16 + g] << 16);
    } else if (t < 64) {
      int tp = t - 32, jp = tp >> 4, g = tp & 15;
      v = (unsigned)slotP[32*jp + g] | ((unsigned)slotP[32*jp + 16 + g] << 16);
    } else if (t == 64) v = ho | (fl << 16);
    else if (t < 73) v = exN[t - 65];
    else if (t < 81) v = exP[t - 73];
    else v = 0;
    rec[t] = v;
  }
}

struct ENT { unsigned w0, w1, w2, w3, mh; };
struct RDv { h2 n0,n1,n2,n3,p0,p1,p2,p3,pv; unsigned mh; };
struct ST  { h2 braw, prevraw; unsigned ho, flu; };

static __device__ __forceinline__ ENT ldent(const unsigned* ents, int c, int g) {
  const unsigned* rec = ents + (size_t)c * RSTR;
  ENT e;
  e.w0 = rec[g]; e.w1 = rec[16+g]; e.w2 = rec[32+g]; e.w3 = rec[48+g];
  e.mh = rec[64];
  return e;
}
static __device__ __forceinline__ void issue_reads(const ENT& E, const char* Pb,
                                                   unsigned pr4, RDv& R) {
  R.n0 = *(const h2*)(Pb + ((E.w0 & 0xFFFFu) + pr4));
  R.n1 = *(const h2*)(Pb + ((E.w0 >> 16)     + pr4));
  R.n2 = *(const h2*)(Pb + ((E.w1 & 0xFFFFu) + pr4));
  R.n3 = *(const h2*)(Pb + ((E.w1 >> 16)     + pr4));
  R.p0 = *(const h2*)(Pb + ((E.w2 & 0xFFFFu) + pr4));
  R.p1 = *(const h2*)(Pb + ((E.w2 >> 16)     + pr4));
  R.p2 = *(const h2*)(Pb + ((E.w3 & 0xFFFFu) + pr4));
  R.p3 = *(const h2*)(Pb + ((E.w3 >> 16)     + pr4));
  R.pv = *(const h2*)(Pb + ((E.mh & 0xFFFFu) + pr4));
  R.mh = E.mh;
}
static __device__ __forceinline__ void combine(const RDv& R, const unsigned* ents,
                                               int c, const char* Pb, unsigned pr4, ST& S) {
  h2 aN = hmax2(hmax2(R.n0, R.n1), hmax2(R.n2, R.n3));
  h2 aP = hmin2(hmin2(R.p0, R.p1), hmin2(R.p2, R.p3));
  unsigned flu = ((unsigned)__builtin_amdgcn_readfirstlane((int)R.mh)) >> 16;
  if (flu & 0x7F80u) {                        // rare extras tail (uniform)
    const unsigned* rec = ents + (size_t)c * RSTR;
    unsigned xn = (flu >> 7) & 15u, xp = (flu >> 11) & 15u;
    for (unsigned j = 0; j < xn; ++j) aN = hmax2(aN, *(const h2*)(Pb + (rec[65+j] + pr4)));
    for (unsigned j = 0; j < xp; ++j) aP = hmin2(aP, *(const h2*)(Pb + (rec[73+j] + pr4)));
  }
  const h2 one2 = {(_Float16)1.f, (_Float16)1.f};
  h2 bp = hmax2(aN, one2 - aP);               // >= 0 by construction
  bp = rormax<0x121>(bp);                     // row_ror:1
  bp = rormax<0x122>(bp);                     // row_ror:2
  bp = rormax<0x124>(bp);                     // row_ror:4
  bp = rormax<0x128>(bp);                     // row_ror:8
  S.braw = bp; S.prevraw = R.pv; S.ho = R.mh & 0xFFFFu; S.flu = flu;
}
static __device__ __forceinline__ h2 finalize(const ST& S, h2 up1, h2 up2,
                                              char* Pb, unsigned pr4, int lane) {
  const h2 one2 = {(_Float16)1.f, (_Float16)1.f};
  unsigned fl = S.flu;
  unsigned mN1 = 0u-((fl>>1)&1u), mP1 = 0u-((fl>>2)&1u);
  unsigned mN2 = 0u-((fl>>3)&1u), mP2 = 0u-((fl>>4)&1u);
  h2 b = S.braw;
  b = hmax2(b, u2h(h2u(up1) & mN1));
  b = hmax2(b, u2h(h2u(one2 - up1) & mP1));
  b = hmax2(b, u2h(h2u(up2) & mN2));
  b = hmax2(b, u2h(h2u(one2 - up2) & mP2));
  unsigned mR1 = 0u-((fl>>5)&1u), mR2 = 0u-((fl>>6)&1u), mRn = ~(mR1|mR2);
  h2 prev = u2h((h2u(up1)&mR1) | (h2u(up2)&mR2) | (h2u(S.prevraw)&mRn));
  unsigned ms = 0u-(fl&1u);
  unsigned hi = h2u(hmax2(prev, one2 - b));
  unsigned lo = h2u(hmin2(prev, b));
  h2 upd = u2h((hi&ms) | (lo&~ms));
  if ((lane & 15) == 0 && !(fl & 0x8000u))
    *(h2*)(Pb + S.ho + pr4) = upd;
  return upd;
}

__global__ __launch_bounds__(64, 2) void solve_kernel(
    const float* __restrict__ preds,
    const unsigned* __restrict__ ents,
    float* __restrict__ out) {
  __shared__ char Pb[LDSB];
  const int lane = threadIdx.x;
  const unsigned pr4 = (unsigned)(lane >> 4) * 4u;   // row-pair byte offset
  const int r2 = lane >> 4, cs = lane & 15;
  const size_t row0 = (size_t)blockIdx.x * ROWS;

  if (lane < 4)      *(unsigned*)(Pb + ZOFF + lane*4) = 0u;
  else if (lane < 8) *(unsigned*)(Pb + OOFF + (lane-4)*4) = 0x3C003C00u;

  // stage in: [atom][8 rows] fp16
  for (int i = 0; i < 16; ++i) {
    int a = i*32 + cs*2;
    float2 v0 = *(const float2*)(preds + (row0 + 2*r2)     * NUM + a);
    float2 v1 = *(const float2*)(preds + (row0 + 2*r2 + 1) * NUM + a);
    h2 w0 = {(_Float16)v0.x, (_Float16)v1.x};
    h2 w1 = {(_Float16)v0.y, (_Float16)v1.y};
    *(h2*)(Pb + a*16 + r2*4) = w0;
    *(h2*)(Pb + (a+1)*16 + r2*4) = w1;
  }
  __syncthreads();

  const int g = lane & 15;
  ENT E0 = ldent(ents, 0, g), E1 = ldent(ents, 1, g);
  ENT E2 = ldent(ents, 2, g), E3 = ldent(ents, 3, g);
  RDv RA, RB; ST S0, S1;
  issue_reads(E0, Pb, pr4, RA);
  issue_reads(E1, Pb, pr4, RB);
  combine(RA, ents, 0, Pb, pr4, S0);
  h2 up1 = (h2)0.0f, up2 = (h2)0.0f;

  #pragma unroll 1
  for (int i = 0; i < CONS; i += 2) {
    issue_reads(E2, Pb, pr4, RA);                                      // reads(i+2)
    { h2 u = finalize(S0, up1, up2, Pb, pr4, lane); up2 = up1; up1 = u; }  // c=i
    combine(RB, ents, i+1, Pb, pr4, S1);
    E2 = ldent(ents, i+4, g);
    issue_reads(E3, Pb, pr4, RB);                                      // reads(i+3)
    { h2 u = finalize(S1, up1, up2, Pb, pr4, lane); up2 = up1; up1 = u; }  // c=i+1
    combine(RA, ents, i+2, Pb, pr4, S0);
    E3 = ldent(ents, i+5, g);
  }

  __syncthreads();
  for (int i = 0; i < 16; ++i) {
    int a = i*32 + cs*2;
    h2 w0 = *(const h2*)(Pb + a*16 + r2*4);
    h2 w1 = *(const h2*)(Pb + (a+1)*16 + r2*4);
    float2 v0 = {(float)w0.x, (float)w1.x};
    float2 v1 = {(float)w0.y, (float)w1.y};
    *(float2*)(out + (row0 + 2*r2)     * NUM + a) = v0;
    *(float2*)(out + (row0 + 2*r2 + 1) * NUM + a) = v1;
  }
}

extern "C" void kernel_launch(void* const* d_in, const int* in_sizes, int n_in,
                              void* d_out, int out_size, void* d_ws, size_t ws_size,
                              hipStream_t stream) {
  (void)in_sizes; (void)n_in; (void)out_size; (void)ws_size;
  const float* preds     = (const float*)d_in[0];
  const float* pos       = (const float*)d_in[1];
  const float* neg       = (const float*)d_in[2];
  const int*   head_atom = (const int*)d_in[3];
  const int*   head_sign = (const int*)d_in[4];

  unsigned* ents = (unsigned*)d_ws;      // NPAD * RSTR * 4 ≈ 173 KB

  prep_kernel<<<NPAD, 64, 0, stream>>>(pos, neg, head_atom, head_sign, ents);
  solve_kernel<<<BATCH / ROWS, 64, 0, stream>>>(preds, ents, (float*)d_out);
}